// Round 1
// baseline (578.718 us; speedup 1.0000x reference)
//
#include <hip/hip_runtime.h>
#include <math.h>

#define NN 128
#define TB 32
#define THREADS 256

// ---------------------------------------------------------------------------
// Build one unitary: one block (64 threads) per ROW of U.
// (U @ L)[r,:] depends only on U[r,:], so each row composes the 128 layers
// independently with the row held in LDS.
// input_phases (if non-null) are folded into the rows of U (diag(e^{i p}) @ U);
// output_phases are folded into the columns at the end.
// U stored row-major [k][j] as float2 (re, im).
// ---------------------------------------------------------------------------
__global__ __launch_bounds__(64) void build_unitary_kernel(
    const float* __restrict__ mzi,
    const float* __restrict__ outph,
    const float* __restrict__ inph,   // nullptr for stages 2,3
    float2* __restrict__ U)
{
    __shared__ float2 u[NN];
    const int r = blockIdx.x;
    const int t = threadIdx.x;

    for (int j = t; j < NN; j += 64) {
        float2 v = make_float2(0.f, 0.f);
        if (j == r) {
            if (inph != nullptr) {
                float p = inph[r];
                v.x = cosf(p); v.y = sinf(p);
            } else {
                v.x = 1.f;
            }
        }
        u[j] = v;
    }
    __syncthreads();

    for (int layer = 0; layer < NN; ++layer) {
        const int start = layer & 1;
        const int m = (NN - start) >> 1;               // 64 even / 63 odd
        const int off = (layer >> 1) * 254 + start * 128;
        const int p = start + 2 * t;
        const bool active = (t < m);
        float2 np = make_float2(0.f, 0.f);
        float2 nq = make_float2(0.f, 0.f);
        if (active) {
            float theta = mzi[off + 2 * t];
            float phi   = mzi[off + 2 * t + 1];
            float ct = cosf(theta), st = sinf(theta);
            float er = cosf(phi),  ei = sinf(phi);
            float2 a = u[p];
            float2 b = u[p + 1];
            // u[p]   = a*ct*e^{i phi} + b*st
            np.x = ct * (a.x * er - a.y * ei) + st * b.x;
            np.y = ct * (a.x * ei + a.y * er) + st * b.y;
            // u[p+1] = a*st - b*ct*conj(e^{i phi})
            nq.x = st * a.x - ct * (b.x * er + b.y * ei);
            nq.y = st * a.y - ct * (b.y * er - b.x * ei);
        }
        __syncthreads();
        if (active) { u[p] = np; u[p + 1] = nq; }
        __syncthreads();
    }

    for (int j = t; j < NN; j += 64) {
        float p = outph[j];
        float er = cosf(p), ei = sinf(p);
        float2 v = u[j];
        float2 w;
        w.x = v.x * er - v.y * ei;
        w.y = v.x * ei + v.y * er;
        U[r * NN + j] = w;
    }
}

// WT[j][n] = W[n][j], W is [N][2N], WT is [2N][N]
__global__ __launch_bounds__(NN) void transpose_w_kernel(
    const float* __restrict__ W, float* __restrict__ WT)
{
    int j = blockIdx.x;     // 0..2N-1
    int n = threadIdx.x;    // 0..N-1
    WT[j * NN + n] = W[n * (2 * NN) + j];
}

// ---------------------------------------------------------------------------
// Fused main kernel: per block, TB=32 batch rows.
//   z1 = x @ U1 (x real)  -> nofu1 -> z2 = z1 @ U2 -> nofu2 -> z3 = z2 @ U3
//   out = re(z3) @ WT[0:128] + im(z3) @ WT[128:256] + bias
// 256 threads; thread owns a 4x4 (batch x col) register tile.
// ---------------------------------------------------------------------------
__global__ __launch_bounds__(THREADS) void ficonn_main_kernel(
    const float* __restrict__ x,
    const float2* __restrict__ U1,
    const float2* __restrict__ U2,
    const float2* __restrict__ U3,
    const float* __restrict__ alpha1, const float* __restrict__ beta1,
    const float* __restrict__ alpha2, const float* __restrict__ beta2,
    const float* __restrict__ WT,
    const float* __restrict__ bias,
    float* __restrict__ out)
{
    __shared__ float2 zbuf[TB][NN];   // 32 KB
    __shared__ float  xbuf[TB][NN];   // 16 KB

    const int tid = threadIdx.x;
    const int b0 = (tid >> 5) << 2;        // 0,4,...,28
    const int j0 = (tid & 31) << 2;        // 0,4,...,124
    const size_t base = (size_t)blockIdx.x * TB;

    // ---- load x tile (coalesced float4) ----
    {
        const float4* xg = (const float4*)(x + base * NN);
        float4* xs = (float4*)&xbuf[0][0];
        #pragma unroll
        for (int i = 0; i < (TB * NN / 4) / THREADS; ++i)
            xs[tid + i * THREADS] = xg[tid + i * THREADS];
    }
    __syncthreads();

    float accr[4][4], acci[4][4];

    // ================= stage 1: z = x @ U1 (x real) =================
    #pragma unroll
    for (int i = 0; i < 4; ++i)
        #pragma unroll
        for (int j = 0; j < 4; ++j) { accr[i][j] = 0.f; acci[i][j] = 0.f; }

    for (int k = 0; k < NN; ++k) {
        float xv[4];
        #pragma unroll
        for (int i = 0; i < 4; ++i) xv[i] = xbuf[b0 + i][k];
        float4 ua = *(const float4*)&U1[k * NN + j0];
        float4 ub = *(const float4*)&U1[k * NN + j0 + 2];
        float ur[4] = {ua.x, ua.z, ub.x, ub.z};
        float ui[4] = {ua.y, ua.w, ub.y, ub.w};
        #pragma unroll
        for (int i = 0; i < 4; ++i)
            #pragma unroll
            for (int j = 0; j < 4; ++j) {
                accr[i][j] = fmaf(xv[i], ur[j], accr[i][j]);
                acci[i][j] = fmaf(xv[i], ui[j], acci[i][j]);
            }
    }

    // nofu 1
    {
        float av[4], bv[4];
        #pragma unroll
        for (int j = 0; j < 4; ++j) {
            av[j] = fminf(fmaxf(alpha1[j0 + j], 0.f), 10.f);
            bv[j] = fminf(fmaxf(beta1[j0 + j], 0.f), 10.f);
        }
        #pragma unroll
        for (int i = 0; i < 4; ++i)
            #pragma unroll
            for (int j = 0; j < 4; ++j) {
                float I = accr[i][j] * accr[i][j] + acci[i][j] * acci[i][j] + 1e-8f;
                float f = expf(-0.5f * av[j] / (1.f + bv[j] * I));
                accr[i][j] *= f; acci[i][j] *= f;
            }
    }
    __syncthreads();
    #pragma unroll
    for (int i = 0; i < 4; ++i)
        #pragma unroll
        for (int j = 0; j < 4; ++j)
            zbuf[b0 + i][j0 + j] = make_float2(accr[i][j], acci[i][j]);
    __syncthreads();

    // ================= stage 2: z = z @ U2 (complex) =================
    #pragma unroll
    for (int i = 0; i < 4; ++i)
        #pragma unroll
        for (int j = 0; j < 4; ++j) { accr[i][j] = 0.f; acci[i][j] = 0.f; }

    for (int k = 0; k < NN; ++k) {
        float2 zv[4];
        #pragma unroll
        for (int i = 0; i < 4; ++i) zv[i] = zbuf[b0 + i][k];
        float4 ua = *(const float4*)&U2[k * NN + j0];
        float4 ub = *(const float4*)&U2[k * NN + j0 + 2];
        float ur[4] = {ua.x, ua.z, ub.x, ub.z};
        float ui[4] = {ua.y, ua.w, ub.y, ub.w};
        #pragma unroll
        for (int i = 0; i < 4; ++i)
            #pragma unroll
            for (int j = 0; j < 4; ++j) {
                accr[i][j] = fmaf(zv[i].x, ur[j], fmaf(-zv[i].y, ui[j], accr[i][j]));
                acci[i][j] = fmaf(zv[i].x, ui[j], fmaf( zv[i].y, ur[j], acci[i][j]));
            }
    }

    // nofu 2
    {
        float av[4], bv[4];
        #pragma unroll
        for (int j = 0; j < 4; ++j) {
            av[j] = fminf(fmaxf(alpha2[j0 + j], 0.f), 10.f);
            bv[j] = fminf(fmaxf(beta2[j0 + j], 0.f), 10.f);
        }
        #pragma unroll
        for (int i = 0; i < 4; ++i)
            #pragma unroll
            for (int j = 0; j < 4; ++j) {
                float I = accr[i][j] * accr[i][j] + acci[i][j] * acci[i][j] + 1e-8f;
                float f = expf(-0.5f * av[j] / (1.f + bv[j] * I));
                accr[i][j] *= f; acci[i][j] *= f;
            }
    }
    __syncthreads();
    #pragma unroll
    for (int i = 0; i < 4; ++i)
        #pragma unroll
        for (int j = 0; j < 4; ++j)
            zbuf[b0 + i][j0 + j] = make_float2(accr[i][j], acci[i][j]);
    __syncthreads();

    // ================= stage 3: z = z @ U3 (complex) =================
    #pragma unroll
    for (int i = 0; i < 4; ++i)
        #pragma unroll
        for (int j = 0; j < 4; ++j) { accr[i][j] = 0.f; acci[i][j] = 0.f; }

    for (int k = 0; k < NN; ++k) {
        float2 zv[4];
        #pragma unroll
        for (int i = 0; i < 4; ++i) zv[i] = zbuf[b0 + i][k];
        float4 ua = *(const float4*)&U3[k * NN + j0];
        float4 ub = *(const float4*)&U3[k * NN + j0 + 2];
        float ur[4] = {ua.x, ua.z, ub.x, ub.z};
        float ui[4] = {ua.y, ua.w, ub.y, ub.w};
        #pragma unroll
        for (int i = 0; i < 4; ++i)
            #pragma unroll
            for (int j = 0; j < 4; ++j) {
                accr[i][j] = fmaf(zv[i].x, ur[j], fmaf(-zv[i].y, ui[j], accr[i][j]));
                acci[i][j] = fmaf(zv[i].x, ui[j], fmaf( zv[i].y, ur[j], acci[i][j]));
            }
    }
    __syncthreads();
    #pragma unroll
    for (int i = 0; i < 4; ++i)
        #pragma unroll
        for (int j = 0; j < 4; ++j)
            zbuf[b0 + i][j0 + j] = make_float2(accr[i][j], acci[i][j]);
    __syncthreads();

    // ================= final: out = re(z)@WT[0:128] + im(z)@WT[128:256] + b ==
    float o[4][4];
    #pragma unroll
    for (int i = 0; i < 4; ++i)
        #pragma unroll
        for (int j = 0; j < 4; ++j) o[i][j] = 0.f;

    for (int k = 0; k < NN; ++k) {
        float2 zv[4];
        #pragma unroll
        for (int i = 0; i < 4; ++i) zv[i] = zbuf[b0 + i][k];
        float4 wr = *(const float4*)&WT[k * NN + j0];
        float4 wi = *(const float4*)&WT[(k + NN) * NN + j0];
        float wrv[4] = {wr.x, wr.y, wr.z, wr.w};
        float wiv[4] = {wi.x, wi.y, wi.z, wi.w};
        #pragma unroll
        for (int i = 0; i < 4; ++i)
            #pragma unroll
            for (int j = 0; j < 4; ++j)
                o[i][j] = fmaf(zv[i].x, wrv[j], fmaf(zv[i].y, wiv[j], o[i][j]));
    }

    float4 bv = *(const float4*)&bias[j0];
    #pragma unroll
    for (int i = 0; i < 4; ++i) {
        float4 res;
        res.x = o[i][0] + bv.x;
        res.y = o[i][1] + bv.y;
        res.z = o[i][2] + bv.z;
        res.w = o[i][3] + bv.w;
        *(float4*)&out[(base + b0 + i) * NN + j0] = res;
    }
}

extern "C" void kernel_launch(void* const* d_in, const int* in_sizes, int n_in,
                              void* d_out, int out_size, void* d_ws, size_t ws_size,
                              hipStream_t stream)
{
    const float* x      = (const float*)d_in[0];
    const float* inph   = (const float*)d_in[1];
    const float* mzi1   = (const float*)d_in[2];
    const float* outph1 = (const float*)d_in[3];
    const float* alpha1 = (const float*)d_in[4];
    const float* beta1  = (const float*)d_in[5];
    const float* mzi2   = (const float*)d_in[6];
    const float* outph2 = (const float*)d_in[7];
    const float* alpha2 = (const float*)d_in[8];
    const float* beta2  = (const float*)d_in[9];
    const float* mzi3   = (const float*)d_in[10];
    const float* outph3 = (const float*)d_in[11];
    const float* W      = (const float*)d_in[12];
    const float* bias   = (const float*)d_in[13];

    const int B = in_sizes[0] / NN;

    float2* U1 = (float2*)d_ws;
    float2* U2 = U1 + NN * NN;
    float2* U3 = U2 + NN * NN;
    float*  WT = (float*)(U3 + NN * NN);

    build_unitary_kernel<<<NN, 64, 0, stream>>>(mzi1, outph1, inph, U1);
    build_unitary_kernel<<<NN, 64, 0, stream>>>(mzi2, outph2, nullptr, U2);
    build_unitary_kernel<<<NN, 64, 0, stream>>>(mzi3, outph3, nullptr, U3);
    transpose_w_kernel<<<2 * NN, NN, 0, stream>>>(W, WT);

    ficonn_main_kernel<<<B / TB, THREADS, 0, stream>>>(
        x, U1, U2, U3, alpha1, beta1, alpha2, beta2, WT, bias, (float*)d_out);
}

// Round 2
// 110.420 us; speedup vs baseline: 5.2411x; 5.2411x over previous
//
#include <hip/hip_runtime.h>
#include <math.h>

typedef __attribute__((ext_vector_type(8))) short bf16x8;
typedef __attribute__((ext_vector_type(4))) float f32x4;
typedef unsigned short u16;

__device__ __forceinline__ unsigned short f2bf(float f) {
    unsigned u = __builtin_bit_cast(unsigned, f);
    u += 0x7fffu + ((u >> 16) & 1u);          // round-to-nearest-even
    return (unsigned short)(u >> 16);
}

// ---------------------------------------------------------------------------
// Prep 1: sin/cos table for all MZIs of all 3 meshes (+ pack P4 from W).
// trig[(s*128+L)*64 + t] = {cos th, sin th, cos phi, sin phi}
// P4: final real matrix [128 cols n][256 k] col-major bf16.
//   row(re,j) = (j>>4)*32 + (j&15), row(im,j) = +16
// ---------------------------------------------------------------------------
__global__ __launch_bounds__(128) void prep_trig_kernel(
    const float* __restrict__ mzi1, const float* __restrict__ mzi2,
    const float* __restrict__ mzi3, const float* __restrict__ W,
    float4* __restrict__ trig, u16* __restrict__ P4)
{
    const int b = blockIdx.x, t = threadIdx.x;
    if (b < 384) {
        if (t >= 64) return;
        const int s = b >> 7, L = b & 127;
        const float* mzi = (s == 0) ? mzi1 : ((s == 1) ? mzi2 : mzi3);
        const int start = L & 1;
        const int m = (128 - start) >> 1;
        float4 v = make_float4(1.f, 0.f, 1.f, 0.f);
        if (t < m) {
            const int off = (L >> 1) * 254 + start * 128 + 2 * t;
            float th = mzi[off], ph = mzi[off + 1];
            float st, ct, sp, cp;
            __sincosf(th, &st, &ct);
            __sincosf(ph, &sp, &cp);
            v = make_float4(ct, st, cp, sp);
        }
        trig[b * 64 + t] = v;
    } else {
        const int n = b - 384;           // output col 0..127
        const int j = t;                  // complex feature 0..127
        const int rre = ((j >> 4) * 32) + (j & 15);
        P4[n * 256 + rre]      = f2bf(W[n * 256 + j]);
        P4[n * 256 + rre + 16] = f2bf(W[n * 256 + j + 128]);
    }
}

// ---------------------------------------------------------------------------
// Prep 2: build row r of mesh s via register+shuffle layer composition,
// then pack to bf16 weight matrices in the block-16 interleaved real form.
// Thread t owns complex row elements j=2t, 2t+1.
// P1: [256 cols][128 k]; P2,P3: [256 cols][256 k]  (col-major, contiguous k)
// ---------------------------------------------------------------------------
__global__ __launch_bounds__(64) void build_pack_kernel(
    const float* __restrict__ inph,
    const float* __restrict__ outph1, const float* __restrict__ outph2,
    const float* __restrict__ outph3,
    const float4* __restrict__ trig,
    u16* __restrict__ P1, u16* __restrict__ P2, u16* __restrict__ P3)
{
    const int s = blockIdx.x >> 7, r = blockIdx.x & 127, t = threadIdx.x;
    const float4* tg = trig + s * 128 * 64;

    float2 a = make_float2(0.f, 0.f), b2 = make_float2(0.f, 0.f);
    if (s == 0) {
        float sp, cp; __sincosf(inph[r], &sp, &cp);
        if (2 * t == r)     a  = make_float2(cp, sp);
        if (2 * t + 1 == r) b2 = make_float2(cp, sp);
    } else {
        if (2 * t == r)     a.x  = 1.f;
        if (2 * t + 1 == r) b2.x = 1.f;
    }

    float4 tv[4];
    #pragma unroll
    for (int i = 0; i < 4; ++i) tv[i] = tg[i * 64 + t];

    #pragma unroll 4
    for (int L = 0; L < 128; ++L) {
        const float4 c = tv[L & 3];
        if (L < 124) tv[L & 3] = tg[(L + 4) * 64 + t];
        if ((L & 1) == 0) {
            // pair (u[2t], u[2t+1]) = (a, b2): thread-local
            float pr = c.x * (a.x * c.z - a.y * c.w) + c.y * b2.x;
            float pi = c.x * (a.x * c.w + a.y * c.z) + c.y * b2.y;
            float qr = c.y * a.x - c.x * (b2.x * c.z + b2.y * c.w);
            float qi = c.y * a.y - c.x * (b2.y * c.z - b2.x * c.w);
            a = make_float2(pr, pi); b2 = make_float2(qr, qi);
        } else {
            // pair (u[2t+1], u[2t+2]) = (b2_t, a_{t+1}); MZI t active for t<63
            float2 an;
            an.x = __shfl_down(a.x, 1); an.y = __shfl_down(a.y, 1);
            float pr = c.x * (b2.x * c.z - b2.y * c.w) + c.y * an.x;
            float pi = c.x * (b2.x * c.w + b2.y * c.z) + c.y * an.y;
            float qr = c.y * b2.x - c.x * (an.x * c.z + an.y * c.w);
            float qi = c.y * b2.y - c.x * (an.y * c.z - an.x * c.w);
            if (t < 63) b2 = make_float2(pr, pi);
            float2 qs;
            qs.x = __shfl_up(qr, 1); qs.y = __shfl_up(qi, 1);
            if (t >= 1) a = qs;
        }
    }

    const float* outph = (s == 0) ? outph1 : ((s == 1) ? outph2 : outph3);
    #pragma unroll
    for (int h = 0; h < 2; ++h) {
        const int j = 2 * t + h;
        float2 w = h ? b2 : a;
        float sp, cp; __sincosf(outph[j], &sp, &cp);
        const float wr = w.x * cp - w.y * sp;
        const float wi = w.x * sp + w.y * cp;
        const int cre = ((j >> 4) * 32) + (j & 15);
        if (s == 0) {
            P1[cre * 128 + r]        = f2bf(wr);
            P1[(cre + 16) * 128 + r] = f2bf(wi);
        } else {
            u16* P = (s == 1) ? P2 : P3;
            const int rre = ((r >> 4) * 32) + (r & 15);
            P[cre * 256 + rre]             = f2bf(wr);
            P[cre * 256 + rre + 16]        = f2bf(-wi);
            P[(cre + 16) * 256 + rre]      = f2bf(wi);
            P[(cre + 16) * 256 + rre + 16] = f2bf(wr);
        }
    }
}

// ---------------------------------------------------------------------------
// Main fused kernel. 512 threads = 8 waves (2 M x 4 N), 128 batch rows/block.
// Wave tile 64x64. Stage outputs round-trip via XOR-swizzled LDS (bf16).
// Weights read directly from L2 (pre-packed col-major bf16).
// ---------------------------------------------------------------------------
__global__ __launch_bounds__(512, 2) void ficonn_mfma_kernel(
    const float* __restrict__ x,
    const u16* __restrict__ P1, const u16* __restrict__ P2,
    const u16* __restrict__ P3, const u16* __restrict__ P4,
    const float* __restrict__ al1, const float* __restrict__ be1,
    const float* __restrict__ al2, const float* __restrict__ be2,
    const float* __restrict__ bias, float* __restrict__ out)
{
    __shared__ __align__(16) char zA[65536];   // [128 rows][256 cols] bf16, swizzled

    const int tid  = threadIdx.x;
    const int lane = tid & 63;
    const int wave = tid >> 6;
    const int l16  = lane & 15;
    const int kg   = lane >> 4;
    const int wm   = wave >> 2;       // 0..1
    const int wn   = wave & 3;        // 0..3
    const int mb   = wm * 64;
    const int nb   = wn * 64;
    const size_t rowBase = (size_t)blockIdx.x * 128;

    float av1[2], bv1[2], av2[2], bv2[2];
    #pragma unroll
    for (int u = 0; u < 2; ++u) {
        const int j = wn * 32 + u * 16 + l16;
        av1[u] = 0.5f * fminf(fmaxf(al1[j], 0.f), 10.f);
        bv1[u] = fminf(fmaxf(be1[j], 0.f), 10.f);
        av2[u] = 0.5f * fminf(fmaxf(al2[j], 0.f), 10.f);
        bv2[u] = fminf(fmaxf(be2[j], 0.f), 10.f);
    }

    f32x4 acc[4][4];

    // ================= stage 1: A = x (global fp32 -> bf16), B = P1, K=128 ==
    #pragma unroll
    for (int mt = 0; mt < 4; ++mt)
        #pragma unroll
        for (int nt = 0; nt < 4; ++nt) acc[mt][nt] = (f32x4){0.f, 0.f, 0.f, 0.f};

    #pragma unroll
    for (int ks = 0; ks < 4; ++ks) {
        const int k0 = ks * 32 + kg * 8;
        bf16x8 A[4];
        #pragma unroll
        for (int mt = 0; mt < 4; ++mt) {
            const float* p = x + (rowBase + mb + mt * 16 + l16) * 128 + k0;
            float4 f0 = *(const float4*)p;
            float4 f1 = *(const float4*)(p + 4);
            bf16x8 t8;
            t8[0] = (short)f2bf(f0.x); t8[1] = (short)f2bf(f0.y);
            t8[2] = (short)f2bf(f0.z); t8[3] = (short)f2bf(f0.w);
            t8[4] = (short)f2bf(f1.x); t8[5] = (short)f2bf(f1.y);
            t8[6] = (short)f2bf(f1.z); t8[7] = (short)f2bf(f1.w);
            A[mt] = t8;
        }
        #pragma unroll
        for (int nt = 0; nt < 4; ++nt) {
            bf16x8 Bf = *(const bf16x8*)&P1[(nb + nt * 16 + l16) * 128 + k0];
            #pragma unroll
            for (int mt = 0; mt < 4; ++mt)
                acc[mt][nt] = __builtin_amdgcn_mfma_f32_16x16x32_bf16(A[mt], Bf, acc[mt][nt], 0, 0, 0);
        }
    }

    // nofu1 + store to zA
    #pragma unroll
    for (int mt = 0; mt < 4; ++mt)
        #pragma unroll
        for (int u = 0; u < 2; ++u)
            #pragma unroll
            for (int r = 0; r < 4; ++r) {
                float re = acc[mt][2 * u][r], im = acc[mt][2 * u + 1][r];
                const float f = __expf(-av1[u] / (1.f + bv1[u] * (re * re + im * im + 1e-8f)));
                re *= f; im *= f;
                const int row = mb + mt * 16 + kg * 4 + r;
                const int colRe = nb + u * 32 + l16;
                const unsigned sw = (unsigned)(row & 31) << 4;
                *(u16*)(zA + (((unsigned)(row * 512 + colRe * 2)) ^ sw)) = f2bf(re);
                *(u16*)(zA + (((unsigned)(row * 512 + (colRe + 16) * 2)) ^ sw)) = f2bf(im);
            }
    __syncthreads();

    // ================= stage 2: A = zA, B = P2, K=256 =======================
    #pragma unroll
    for (int mt = 0; mt < 4; ++mt)
        #pragma unroll
        for (int nt = 0; nt < 4; ++nt) acc[mt][nt] = (f32x4){0.f, 0.f, 0.f, 0.f};

    #pragma unroll
    for (int ks = 0; ks < 8; ++ks) {
        const int k0 = ks * 32 + kg * 8;
        bf16x8 A[4];
        #pragma unroll
        for (int mt = 0; mt < 4; ++mt) {
            const int row = mb + mt * 16 + l16;
            const unsigned byte = ((unsigned)(row * 512 + k0 * 2)) ^ ((unsigned)(row & 31) << 4);
            A[mt] = *(const bf16x8*)(zA + byte);
        }
        #pragma unroll
        for (int nt = 0; nt < 4; ++nt) {
            bf16x8 Bf = *(const bf16x8*)&P2[(nb + nt * 16 + l16) * 256 + k0];
            #pragma unroll
            for (int mt = 0; mt < 4; ++mt)
                acc[mt][nt] = __builtin_amdgcn_mfma_f32_16x16x32_bf16(A[mt], Bf, acc[mt][nt], 0, 0, 0);
        }
    }
    __syncthreads();   // all zA reads done before overwrite

    // nofu2 + store to zA
    #pragma unroll
    for (int mt = 0; mt < 4; ++mt)
        #pragma unroll
        for (int u = 0; u < 2; ++u)
            #pragma unroll
            for (int r = 0; r < 4; ++r) {
                float re = acc[mt][2 * u][r], im = acc[mt][2 * u + 1][r];
                const float f = __expf(-av2[u] / (1.f + bv2[u] * (re * re + im * im + 1e-8f)));
                re *= f; im *= f;
                const int row = mb + mt * 16 + kg * 4 + r;
                const int colRe = nb + u * 32 + l16;
                const unsigned sw = (unsigned)(row & 31) << 4;
                *(u16*)(zA + (((unsigned)(row * 512 + colRe * 2)) ^ sw)) = f2bf(re);
                *(u16*)(zA + (((unsigned)(row * 512 + (colRe + 16) * 2)) ^ sw)) = f2bf(im);
            }
    __syncthreads();

    // ================= stage 3: A = zA, B = P3, K=256 (no nofu) =============
    #pragma unroll
    for (int mt = 0; mt < 4; ++mt)
        #pragma unroll
        for (int nt = 0; nt < 4; ++nt) acc[mt][nt] = (f32x4){0.f, 0.f, 0.f, 0.f};

    #pragma unroll
    for (int ks = 0; ks < 8; ++ks) {
        const int k0 = ks * 32 + kg * 8;
        bf16x8 A[4];
        #pragma unroll
        for (int mt = 0; mt < 4; ++mt) {
            const int row = mb + mt * 16 + l16;
            const unsigned byte = ((unsigned)(row * 512 + k0 * 2)) ^ ((unsigned)(row & 31) << 4);
            A[mt] = *(const bf16x8*)(zA + byte);
        }
        #pragma unroll
        for (int nt = 0; nt < 4; ++nt) {
            bf16x8 Bf = *(const bf16x8*)&P3[(nb + nt * 16 + l16) * 256 + k0];
            #pragma unroll
            for (int mt = 0; mt < 4; ++mt)
                acc[mt][nt] = __builtin_amdgcn_mfma_f32_16x16x32_bf16(A[mt], Bf, acc[mt][nt], 0, 0, 0);
        }
    }
    __syncthreads();

    // store z3 (plain) to zA
    #pragma unroll
    for (int mt = 0; mt < 4; ++mt)
        #pragma unroll
        for (int u = 0; u < 2; ++u)
            #pragma unroll
            for (int r = 0; r < 4; ++r) {
                const int row = mb + mt * 16 + kg * 4 + r;
                const int colRe = nb + u * 32 + l16;
                const unsigned sw = (unsigned)(row & 31) << 4;
                *(u16*)(zA + (((unsigned)(row * 512 + colRe * 2)) ^ sw)) = f2bf(acc[mt][2 * u][r]);
                *(u16*)(zA + (((unsigned)(row * 512 + (colRe + 16) * 2)) ^ sw)) = f2bf(acc[mt][2 * u + 1][r]);
            }
    __syncthreads();

    // ================= final: A = zA, B = P4 [128 cols][256 k], Nw=32 =======
    f32x4 facc[4][2];
    #pragma unroll
    for (int mt = 0; mt < 4; ++mt)
        #pragma unroll
        for (int nt = 0; nt < 2; ++nt) facc[mt][nt] = (f32x4){0.f, 0.f, 0.f, 0.f};

    const int nb2 = wn * 32;
    #pragma unroll
    for (int ks = 0; ks < 8; ++ks) {
        const int k0 = ks * 32 + kg * 8;
        bf16x8 A[4];
        #pragma unroll
        for (int mt = 0; mt < 4; ++mt) {
            const int row = mb + mt * 16 + l16;
            const unsigned byte = ((unsigned)(row * 512 + k0 * 2)) ^ ((unsigned)(row & 31) << 4);
            A[mt] = *(const bf16x8*)(zA + byte);
        }
        #pragma unroll
        for (int nt = 0; nt < 2; ++nt) {
            bf16x8 Bf = *(const bf16x8*)&P4[(nb2 + nt * 16 + l16) * 256 + k0];
            #pragma unroll
            for (int mt = 0; mt < 4; ++mt)
                facc[mt][nt] = __builtin_amdgcn_mfma_f32_16x16x32_bf16(A[mt], Bf, facc[mt][nt], 0, 0, 0);
        }
    }

    const float bcol0 = bias[nb2 + l16];
    const float bcol1 = bias[nb2 + 16 + l16];
    #pragma unroll
    for (int mt = 0; mt < 4; ++mt)
        #pragma unroll
        for (int r = 0; r < 4; ++r) {
            const size_t row = rowBase + mb + mt * 16 + kg * 4 + r;
            out[row * 128 + nb2 + l16]      = facc[mt][0][r] + bcol0;
            out[row * 128 + nb2 + 16 + l16] = facc[mt][1][r] + bcol1;
        }
}

extern "C" void kernel_launch(void* const* d_in, const int* in_sizes, int n_in,
                              void* d_out, int out_size, void* d_ws, size_t ws_size,
                              hipStream_t stream)
{
    const float* x      = (const float*)d_in[0];
    const float* inph   = (const float*)d_in[1];
    const float* mzi1   = (const float*)d_in[2];
    const float* outph1 = (const float*)d_in[3];
    const float* alpha1 = (const float*)d_in[4];
    const float* beta1  = (const float*)d_in[5];
    const float* mzi2   = (const float*)d_in[6];
    const float* outph2 = (const float*)d_in[7];
    const float* alpha2 = (const float*)d_in[8];
    const float* beta2  = (const float*)d_in[9];
    const float* mzi3   = (const float*)d_in[10];
    const float* outph3 = (const float*)d_in[11];
    const float* W      = (const float*)d_in[12];
    const float* bias   = (const float*)d_in[13];

    const int B = in_sizes[0] / 128;

    // ws layout
    float4* trig = (float4*)d_ws;                          // 3*128*64*16 = 393216 B
    u16* P1 = (u16*)((char*)d_ws + 393216);                // 65536 B
    u16* P2 = P1 + 32768;                                  // 131072 B
    u16* P3 = P2 + 65536;                                  // 131072 B
    u16* P4 = P3 + 65536;                                  // 65536 B

    prep_trig_kernel<<<512, 128, 0, stream>>>(mzi1, mzi2, mzi3, W, trig, P4);
    build_pack_kernel<<<384, 64, 0, stream>>>(inph, outph1, outph2, outph3, trig, P1, P2, P3);
    ficonn_mfma_kernel<<<B / 128, 512, 0, stream>>>(
        x, P1, P2, P3, P4, alpha1, beta1, alpha2, beta2, bias, (float*)d_out);
}

// Round 3
// 110.343 us; speedup vs baseline: 5.2447x; 1.0007x over previous
//
#include <hip/hip_runtime.h>
#include <math.h>

typedef __attribute__((ext_vector_type(8))) short bf16x8;
typedef __attribute__((ext_vector_type(4))) float f32x4;
typedef unsigned short u16;

__device__ __forceinline__ unsigned short f2bf(float f) {
    unsigned u = __builtin_bit_cast(unsigned, f);
    u += 0x7fffu + ((u >> 16) & 1u);          // round-to-nearest-even
    return (unsigned short)(u >> 16);
}

// ---------------------------------------------------------------------------
// Prep 1: sin/cos table for all MZIs of all 3 meshes (+ pack P4 from W).
// trig[(s*128+L)*64 + t] = {cos th, sin th, cos phi, sin phi}
// P4: final real matrix [128 cols n][256 k] col-major bf16.
//   row(re,j) = (j>>4)*32 + (j&15), row(im,j) = +16
// ---------------------------------------------------------------------------
__global__ __launch_bounds__(128) void prep_trig_kernel(
    const float* __restrict__ mzi1, const float* __restrict__ mzi2,
    const float* __restrict__ mzi3, const float* __restrict__ W,
    float4* __restrict__ trig, u16* __restrict__ P4)
{
    const int b = blockIdx.x, t = threadIdx.x;
    if (b < 384) {
        if (t >= 64) return;
        const int s = b >> 7, L = b & 127;
        const float* mzi = (s == 0) ? mzi1 : ((s == 1) ? mzi2 : mzi3);
        const int start = L & 1;
        const int m = (128 - start) >> 1;
        float4 v = make_float4(1.f, 0.f, 1.f, 0.f);
        if (t < m) {
            const int off = (L >> 1) * 254 + start * 128 + 2 * t;
            float th = mzi[off], ph = mzi[off + 1];
            float st, ct, sp, cp;
            __sincosf(th, &st, &ct);
            __sincosf(ph, &sp, &cp);
            v = make_float4(ct, st, cp, sp);
        }
        trig[b * 64 + t] = v;
    } else {
        const int n = b - 384;           // output col 0..127
        const int j = t;                  // complex feature 0..127
        const int rre = ((j >> 4) * 32) + (j & 15);
        P4[n * 256 + rre]      = f2bf(W[n * 256 + j]);
        P4[n * 256 + rre + 16] = f2bf(W[n * 256 + j + 128]);
    }
}

// ---------------------------------------------------------------------------
// Prep 2: build row r of mesh s via register+shuffle layer composition,
// then pack to bf16 weight matrices in the block-16 interleaved real form.
// Thread t owns complex row elements j=2t, 2t+1.
// P1: [256 cols][128 k]; P2,P3: [256 cols][256 k]  (col-major, contiguous k)
// ---------------------------------------------------------------------------
__global__ __launch_bounds__(64) void build_pack_kernel(
    const float* __restrict__ inph,
    const float* __restrict__ outph1, const float* __restrict__ outph2,
    const float* __restrict__ outph3,
    const float4* __restrict__ trig,
    u16* __restrict__ P1, u16* __restrict__ P2, u16* __restrict__ P3)
{
    const int s = blockIdx.x >> 7, r = blockIdx.x & 127, t = threadIdx.x;
    const float4* tg = trig + s * 128 * 64;

    float2 a = make_float2(0.f, 0.f), b2 = make_float2(0.f, 0.f);
    if (s == 0) {
        float sp, cp; __sincosf(inph[r], &sp, &cp);
        if (2 * t == r)     a  = make_float2(cp, sp);
        if (2 * t + 1 == r) b2 = make_float2(cp, sp);
    } else {
        if (2 * t == r)     a.x  = 1.f;
        if (2 * t + 1 == r) b2.x = 1.f;
    }

    float4 tv[4];
    #pragma unroll
    for (int i = 0; i < 4; ++i) tv[i] = tg[i * 64 + t];

    #pragma unroll 4
    for (int L = 0; L < 128; ++L) {
        const float4 c = tv[L & 3];
        if (L < 124) tv[L & 3] = tg[(L + 4) * 64 + t];
        if ((L & 1) == 0) {
            // pair (u[2t], u[2t+1]) = (a, b2): thread-local
            float pr = c.x * (a.x * c.z - a.y * c.w) + c.y * b2.x;
            float pi = c.x * (a.x * c.w + a.y * c.z) + c.y * b2.y;
            float qr = c.y * a.x - c.x * (b2.x * c.z + b2.y * c.w);
            float qi = c.y * a.y - c.x * (b2.y * c.z - b2.x * c.w);
            a = make_float2(pr, pi); b2 = make_float2(qr, qi);
        } else {
            // pair (u[2t+1], u[2t+2]) = (b2_t, a_{t+1}); MZI t active for t<63
            float2 an;
            an.x = __shfl_down(a.x, 1); an.y = __shfl_down(a.y, 1);
            float pr = c.x * (b2.x * c.z - b2.y * c.w) + c.y * an.x;
            float pi = c.x * (b2.x * c.w + b2.y * c.z) + c.y * an.y;
            float qr = c.y * b2.x - c.x * (an.x * c.z + an.y * c.w);
            float qi = c.y * b2.y - c.x * (an.y * c.z - an.x * c.w);
            if (t < 63) b2 = make_float2(pr, pi);
            float2 qs;
            qs.x = __shfl_up(qr, 1); qs.y = __shfl_up(qi, 1);
            if (t >= 1) a = qs;
        }
    }

    const float* outph = (s == 0) ? outph1 : ((s == 1) ? outph2 : outph3);
    #pragma unroll
    for (int h = 0; h < 2; ++h) {
        const int j = 2 * t + h;
        float2 w = h ? b2 : a;
        float sp, cp; __sincosf(outph[j], &sp, &cp);
        const float wr = w.x * cp - w.y * sp;
        const float wi = w.x * sp + w.y * cp;
        const int cre = ((j >> 4) * 32) + (j & 15);
        if (s == 0) {
            P1[cre * 128 + r]        = f2bf(wr);
            P1[(cre + 16) * 128 + r] = f2bf(wi);
        } else {
            u16* P = (s == 1) ? P2 : P3;
            const int rre = ((r >> 4) * 32) + (r & 15);
            P[cre * 256 + rre]             = f2bf(wr);
            P[cre * 256 + rre + 16]        = f2bf(-wi);
            P[(cre + 16) * 256 + rre]      = f2bf(wi);
            P[(cre + 16) * 256 + rre + 16] = f2bf(wr);
        }
    }
}

// ---------------------------------------------------------------------------
// Main fused kernel. 512 threads = 8 waves (2 M x 4 N), 128 batch rows/block.
// Wave tile 64x64. Stage outputs round-trip via XOR-swizzled LDS (bf16).
// Weights read directly from L2 (pre-packed col-major bf16).
// ---------------------------------------------------------------------------
__global__ __launch_bounds__(512, 2) void ficonn_mfma_kernel(
    const float* __restrict__ x,
    const u16* __restrict__ P1, const u16* __restrict__ P2,
    const u16* __restrict__ P3, const u16* __restrict__ P4,
    const float* __restrict__ al1, const float* __restrict__ be1,
    const float* __restrict__ al2, const float* __restrict__ be2,
    const float* __restrict__ bias, float* __restrict__ out)
{
    __shared__ __align__(16) char zA[65536];   // [128 rows][256 cols] bf16, swizzled

    const int tid  = threadIdx.x;
    const int lane = tid & 63;
    const int wave = tid >> 6;
    const int l16  = lane & 15;
    const int kg   = lane >> 4;
    const int wm   = wave >> 2;       // 0..1
    const int wn   = wave & 3;        // 0..3
    const int mb   = wm * 64;
    const int nb   = wn * 64;
    const size_t rowBase = (size_t)blockIdx.x * 128;

    float av1[2], bv1[2], av2[2], bv2[2];
    #pragma unroll
    for (int u = 0; u < 2; ++u) {
        const int j = wn * 32 + u * 16 + l16;
        av1[u] = 0.5f * fminf(fmaxf(al1[j], 0.f), 10.f);
        bv1[u] = fminf(fmaxf(be1[j], 0.f), 10.f);
        av2[u] = 0.5f * fminf(fmaxf(al2[j], 0.f), 10.f);
        bv2[u] = fminf(fmaxf(be2[j], 0.f), 10.f);
    }

    f32x4 acc[4][4];

    // ================= stage 1: A = x (global fp32 -> bf16), B = P1, K=128 ==
    #pragma unroll
    for (int mt = 0; mt < 4; ++mt)
        #pragma unroll
        for (int nt = 0; nt < 4; ++nt) acc[mt][nt] = (f32x4){0.f, 0.f, 0.f, 0.f};

    #pragma unroll
    for (int ks = 0; ks < 4; ++ks) {
        const int k0 = ks * 32 + kg * 8;
        bf16x8 A[4];
        #pragma unroll
        for (int mt = 0; mt < 4; ++mt) {
            const float* p = x + (rowBase + mb + mt * 16 + l16) * 128 + k0;
            float4 f0 = *(const float4*)p;
            float4 f1 = *(const float4*)(p + 4);
            bf16x8 t8;
            t8[0] = (short)f2bf(f0.x); t8[1] = (short)f2bf(f0.y);
            t8[2] = (short)f2bf(f0.z); t8[3] = (short)f2bf(f0.w);
            t8[4] = (short)f2bf(f1.x); t8[5] = (short)f2bf(f1.y);
            t8[6] = (short)f2bf(f1.z); t8[7] = (short)f2bf(f1.w);
            A[mt] = t8;
        }
        #pragma unroll
        for (int nt = 0; nt < 4; ++nt) {
            bf16x8 Bf = *(const bf16x8*)&P1[(nb + nt * 16 + l16) * 128 + k0];
            #pragma unroll
            for (int mt = 0; mt < 4; ++mt)
                acc[mt][nt] = __builtin_amdgcn_mfma_f32_16x16x32_bf16(A[mt], Bf, acc[mt][nt], 0, 0, 0);
        }
    }

    // nofu1 + store to zA
    #pragma unroll
    for (int mt = 0; mt < 4; ++mt)
        #pragma unroll
        for (int u = 0; u < 2; ++u)
            #pragma unroll
            for (int r = 0; r < 4; ++r) {
                float re = acc[mt][2 * u][r], im = acc[mt][2 * u + 1][r];
                const float f = __expf(-av1[u] / (1.f + bv1[u] * (re * re + im * im + 1e-8f)));
                re *= f; im *= f;
                const int row = mb + mt * 16 + kg * 4 + r;
                const int colRe = nb + u * 32 + l16;
                const unsigned sw = (unsigned)(row & 31) << 4;
                *(u16*)(zA + (((unsigned)(row * 512 + colRe * 2)) ^ sw)) = f2bf(re);
                *(u16*)(zA + (((unsigned)(row * 512 + (colRe + 16) * 2)) ^ sw)) = f2bf(im);
            }
    __syncthreads();

    // ================= stage 2: A = zA, B = P2, K=256 =======================
    #pragma unroll
    for (int mt = 0; mt < 4; ++mt)
        #pragma unroll
        for (int nt = 0; nt < 4; ++nt) acc[mt][nt] = (f32x4){0.f, 0.f, 0.f, 0.f};

    #pragma unroll
    for (int ks = 0; ks < 8; ++ks) {
        const int k0 = ks * 32 + kg * 8;
        bf16x8 A[4];
        #pragma unroll
        for (int mt = 0; mt < 4; ++mt) {
            const int row = mb + mt * 16 + l16;
            const unsigned byte = ((unsigned)(row * 512 + k0 * 2)) ^ ((unsigned)(row & 31) << 4);
            A[mt] = *(const bf16x8*)(zA + byte);
        }
        #pragma unroll
        for (int nt = 0; nt < 4; ++nt) {
            bf16x8 Bf = *(const bf16x8*)&P2[(nb + nt * 16 + l16) * 256 + k0];
            #pragma unroll
            for (int mt = 0; mt < 4; ++mt)
                acc[mt][nt] = __builtin_amdgcn_mfma_f32_16x16x32_bf16(A[mt], Bf, acc[mt][nt], 0, 0, 0);
        }
    }
    __syncthreads();   // all zA reads done before overwrite

    // nofu2 + store to zA
    #pragma unroll
    for (int mt = 0; mt < 4; ++mt)
        #pragma unroll
        for (int u = 0; u < 2; ++u)
            #pragma unroll
            for (int r = 0; r < 4; ++r) {
                float re = acc[mt][2 * u][r], im = acc[mt][2 * u + 1][r];
                const float f = __expf(-av2[u] / (1.f + bv2[u] * (re * re + im * im + 1e-8f)));
                re *= f; im *= f;
                const int row = mb + mt * 16 + kg * 4 + r;
                const int colRe = nb + u * 32 + l16;
                const unsigned sw = (unsigned)(row & 31) << 4;
                *(u16*)(zA + (((unsigned)(row * 512 + colRe * 2)) ^ sw)) = f2bf(re);
                *(u16*)(zA + (((unsigned)(row * 512 + (colRe + 16) * 2)) ^ sw)) = f2bf(im);
            }
    __syncthreads();

    // ================= stage 3: A = zA, B = P3, K=256 (no nofu) =============
    #pragma unroll
    for (int mt = 0; mt < 4; ++mt)
        #pragma unroll
        for (int nt = 0; nt < 4; ++nt) acc[mt][nt] = (f32x4){0.f, 0.f, 0.f, 0.f};

    #pragma unroll
    for (int ks = 0; ks < 8; ++ks) {
        const int k0 = ks * 32 + kg * 8;
        bf16x8 A[4];
        #pragma unroll
        for (int mt = 0; mt < 4; ++mt) {
            const int row = mb + mt * 16 + l16;
            const unsigned byte = ((unsigned)(row * 512 + k0 * 2)) ^ ((unsigned)(row & 31) << 4);
            A[mt] = *(const bf16x8*)(zA + byte);
        }
        #pragma unroll
        for (int nt = 0; nt < 4; ++nt) {
            bf16x8 Bf = *(const bf16x8*)&P3[(nb + nt * 16 + l16) * 256 + k0];
            #pragma unroll
            for (int mt = 0; mt < 4; ++mt)
                acc[mt][nt] = __builtin_amdgcn_mfma_f32_16x16x32_bf16(A[mt], Bf, acc[mt][nt], 0, 0, 0);
        }
    }
    __syncthreads();

    // store z3 (plain) to zA
    #pragma unroll
    for (int mt = 0; mt < 4; ++mt)
        #pragma unroll
        for (int u = 0; u < 2; ++u)
            #pragma unroll
            for (int r = 0; r < 4; ++r) {
                const int row = mb + mt * 16 + kg * 4 + r;
                const int colRe = nb + u * 32 + l16;
                const unsigned sw = (unsigned)(row & 31) << 4;
                *(u16*)(zA + (((unsigned)(row * 512 + colRe * 2)) ^ sw)) = f2bf(acc[mt][2 * u][r]);
                *(u16*)(zA + (((unsigned)(row * 512 + (colRe + 16) * 2)) ^ sw)) = f2bf(acc[mt][2 * u + 1][r]);
            }
    __syncthreads();

    // ================= final: A = zA, B = P4 [128 cols][256 k], Nw=32 =======
    f32x4 facc[4][2];
    #pragma unroll
    for (int mt = 0; mt < 4; ++mt)
        #pragma unroll
        for (int nt = 0; nt < 2; ++nt) facc[mt][nt] = (f32x4){0.f, 0.f, 0.f, 0.f};

    const int nb2 = wn * 32;
    #pragma unroll
    for (int ks = 0; ks < 8; ++ks) {
        const int k0 = ks * 32 + kg * 8;
        bf16x8 A[4];
        #pragma unroll
        for (int mt = 0; mt < 4; ++mt) {
            const int row = mb + mt * 16 + l16;
            const unsigned byte = ((unsigned)(row * 512 + k0 * 2)) ^ ((unsigned)(row & 31) << 4);
            A[mt] = *(const bf16x8*)(zA + byte);
        }
        #pragma unroll
        for (int nt = 0; nt < 2; ++nt) {
            bf16x8 Bf = *(const bf16x8*)&P4[(nb2 + nt * 16 + l16) * 256 + k0];
            #pragma unroll
            for (int mt = 0; mt < 4; ++mt)
                facc[mt][nt] = __builtin_amdgcn_mfma_f32_16x16x32_bf16(A[mt], Bf, facc[mt][nt], 0, 0, 0);
        }
    }

    const float bcol0 = bias[nb2 + l16];
    const float bcol1 = bias[nb2 + 16 + l16];
    #pragma unroll
    for (int mt = 0; mt < 4; ++mt)
        #pragma unroll
        for (int r = 0; r < 4; ++r) {
            const size_t row = rowBase + mb + mt * 16 + kg * 4 + r;
            out[row * 128 + nb2 + l16]      = facc[mt][0][r] + bcol0;
            out[row * 128 + nb2 + 16 + l16] = facc[mt][1][r] + bcol1;
        }
}

extern "C" void kernel_launch(void* const* d_in, const int* in_sizes, int n_in,
                              void* d_out, int out_size, void* d_ws, size_t ws_size,
                              hipStream_t stream)
{
    const float* x      = (const float*)d_in[0];
    const float* inph   = (const float*)d_in[1];
    const float* mzi1   = (const float*)d_in[2];
    const float* outph1 = (const float*)d_in[3];
    const float* alpha1 = (const float*)d_in[4];
    const float* beta1  = (const float*)d_in[5];
    const float* mzi2   = (const float*)d_in[6];
    const float* outph2 = (const float*)d_in[7];
    const float* alpha2 = (const float*)d_in[8];
    const float* beta2  = (const float*)d_in[9];
    const float* mzi3   = (const float*)d_in[10];
    const float* outph3 = (const float*)d_in[11];
    const float* W      = (const float*)d_in[12];
    const float* bias   = (const float*)d_in[13];

    const int B = in_sizes[0] / 128;

    // ws layout
    float4* trig = (float4*)d_ws;                          // 3*128*64*16 = 393216 B
    u16* P1 = (u16*)((char*)d_ws + 393216);                // 65536 B
    u16* P2 = P1 + 32768;                                  // 131072 B
    u16* P3 = P2 + 65536;                                  // 131072 B
    u16* P4 = P3 + 65536;                                  // 65536 B

    prep_trig_kernel<<<512, 128, 0, stream>>>(mzi1, mzi2, mzi3, W, trig, P4);
    build_pack_kernel<<<384, 64, 0, stream>>>(inph, outph1, outph2, outph3, trig, P1, P2, P3);
    ficonn_mfma_kernel<<<B / 128, 512, 0, stream>>>(
        x, P1, P2, P3, P4, alpha1, beta1, alpha2, beta2, bias, (float*)d_out);
}

// Round 4
// 109.192 us; speedup vs baseline: 5.3000x; 1.0105x over previous
//
#include <hip/hip_runtime.h>
#include <math.h>

typedef __attribute__((ext_vector_type(8))) short bf16x8;
typedef __attribute__((ext_vector_type(4))) float f32x4;
typedef unsigned short u16;

__device__ __forceinline__ unsigned short f2bf(float f) {
    unsigned u = __builtin_bit_cast(unsigned, f);
    u += 0x7fffu + ((u >> 16) & 1u);          // round-to-nearest-even
    return (unsigned short)(u >> 16);
}

// ---------------------------------------------------------------------------
// Prep 1: sin/cos table for all MZIs of all 3 meshes (+ pack P4 from W).
// trig[(s*128+L)*64 + t] = {cos th, sin th, cos phi, sin phi}
// P4: final real matrix [128 cols n][256 k] col-major bf16.
//   row(re,j) = (j>>4)*32 + (j&15), row(im,j) = +16
// ---------------------------------------------------------------------------
__global__ __launch_bounds__(128) void prep_trig_kernel(
    const float* __restrict__ mzi1, const float* __restrict__ mzi2,
    const float* __restrict__ mzi3, const float* __restrict__ W,
    float4* __restrict__ trig, u16* __restrict__ P4)
{
    const int b = blockIdx.x, t = threadIdx.x;
    if (b < 384) {
        if (t >= 64) return;
        const int s = b >> 7, L = b & 127;
        const float* mzi = (s == 0) ? mzi1 : ((s == 1) ? mzi2 : mzi3);
        const int start = L & 1;
        const int m = (128 - start) >> 1;
        float4 v = make_float4(1.f, 0.f, 1.f, 0.f);
        if (t < m) {
            const int off = (L >> 1) * 254 + start * 128 + 2 * t;
            float th = mzi[off], ph = mzi[off + 1];
            float st, ct, sp, cp;
            __sincosf(th, &st, &ct);
            __sincosf(ph, &sp, &cp);
            v = make_float4(ct, st, cp, sp);
        }
        trig[b * 64 + t] = v;
    } else {
        const int n = b - 384;           // output col 0..127
        const int j = t;                  // complex feature 0..127
        const int rre = ((j >> 4) * 32) + (j & 15);
        P4[n * 256 + rre]      = f2bf(W[n * 256 + j]);
        P4[n * 256 + rre + 16] = f2bf(W[n * 256 + j + 128]);
    }
}

// ---------------------------------------------------------------------------
// Prep 2: build row r of mesh s via register+shuffle layer composition,
// then pack to bf16 weight matrices in the block-16 interleaved real form.
// Thread t owns complex row elements j=2t, 2t+1.
// P1: [256 cols][128 k]; P2,P3: [256 cols][256 k]  (col-major, contiguous k)
// ---------------------------------------------------------------------------
__global__ __launch_bounds__(64) void build_pack_kernel(
    const float* __restrict__ inph,
    const float* __restrict__ outph1, const float* __restrict__ outph2,
    const float* __restrict__ outph3,
    const float4* __restrict__ trig,
    u16* __restrict__ P1, u16* __restrict__ P2, u16* __restrict__ P3)
{
    const int s = blockIdx.x >> 7, r = blockIdx.x & 127, t = threadIdx.x;
    const float4* tg = trig + s * 128 * 64;

    float2 a = make_float2(0.f, 0.f), b2 = make_float2(0.f, 0.f);
    if (s == 0) {
        float sp, cp; __sincosf(inph[r], &sp, &cp);
        if (2 * t == r)     a  = make_float2(cp, sp);
        if (2 * t + 1 == r) b2 = make_float2(cp, sp);
    } else {
        if (2 * t == r)     a.x  = 1.f;
        if (2 * t + 1 == r) b2.x = 1.f;
    }

    float4 tv[4];
    #pragma unroll
    for (int i = 0; i < 4; ++i) tv[i] = tg[i * 64 + t];

    #pragma unroll 4
    for (int L = 0; L < 128; ++L) {
        const float4 c = tv[L & 3];
        if (L < 124) tv[L & 3] = tg[(L + 4) * 64 + t];
        if ((L & 1) == 0) {
            // pair (u[2t], u[2t+1]) = (a, b2): thread-local
            float pr = c.x * (a.x * c.z - a.y * c.w) + c.y * b2.x;
            float pi = c.x * (a.x * c.w + a.y * c.z) + c.y * b2.y;
            float qr = c.y * a.x - c.x * (b2.x * c.z + b2.y * c.w);
            float qi = c.y * a.y - c.x * (b2.y * c.z - b2.x * c.w);
            a = make_float2(pr, pi); b2 = make_float2(qr, qi);
        } else {
            // pair (u[2t+1], u[2t+2]) = (b2_t, a_{t+1}); MZI t active for t<63
            float2 an;
            an.x = __shfl_down(a.x, 1); an.y = __shfl_down(a.y, 1);
            float pr = c.x * (b2.x * c.z - b2.y * c.w) + c.y * an.x;
            float pi = c.x * (b2.x * c.w + b2.y * c.z) + c.y * an.y;
            float qr = c.y * b2.x - c.x * (an.x * c.z + an.y * c.w);
            float qi = c.y * b2.y - c.x * (an.y * c.z - an.x * c.w);
            if (t < 63) b2 = make_float2(pr, pi);
            float2 qs;
            qs.x = __shfl_up(qr, 1); qs.y = __shfl_up(qi, 1);
            if (t >= 1) a = qs;
        }
    }

    const float* outph = (s == 0) ? outph1 : ((s == 1) ? outph2 : outph3);
    #pragma unroll
    for (int h = 0; h < 2; ++h) {
        const int j = 2 * t + h;
        float2 w = h ? b2 : a;
        float sp, cp; __sincosf(outph[j], &sp, &cp);
        const float wr = w.x * cp - w.y * sp;
        const float wi = w.x * sp + w.y * cp;
        const int cre = ((j >> 4) * 32) + (j & 15);
        if (s == 0) {
            P1[cre * 128 + r]        = f2bf(wr);
            P1[(cre + 16) * 128 + r] = f2bf(wi);
        } else {
            u16* P = (s == 1) ? P2 : P3;
            const int rre = ((r >> 4) * 32) + (r & 15);
            P[cre * 256 + rre]             = f2bf(wr);
            P[cre * 256 + rre + 16]        = f2bf(-wi);
            P[(cre + 16) * 256 + rre]      = f2bf(wi);
            P[(cre + 16) * 256 + rre + 16] = f2bf(wr);
        }
    }
}

// ---------------------------------------------------------------------------
// Main fused kernel. 512 threads = 8 waves (2 M x 4 N), 128 batch rows/block.
// Wave tile 64x64. Stage outputs round-trip via XOR-swizzled LDS (bf16).
// Weights read directly from L2 (pre-packed col-major bf16).
// ---------------------------------------------------------------------------
__global__ __launch_bounds__(512, 2) void ficonn_mfma_kernel(
    const float* __restrict__ x,
    const u16* __restrict__ P1, const u16* __restrict__ P2,
    const u16* __restrict__ P3, const u16* __restrict__ P4,
    const float* __restrict__ al1, const float* __restrict__ be1,
    const float* __restrict__ al2, const float* __restrict__ be2,
    const float* __restrict__ bias, float* __restrict__ out)
{
    __shared__ __align__(16) char zA[65536];   // [128 rows][256 cols] bf16, swizzled

    const int tid  = threadIdx.x;
    const int lane = tid & 63;
    const int wave = tid >> 6;
    const int l16  = lane & 15;
    const int kg   = lane >> 4;
    const int wm   = wave >> 2;       // 0..1
    const int wn   = wave & 3;        // 0..3
    const int mb   = wm * 64;
    const int nb   = wn * 64;
    const size_t rowBase = (size_t)blockIdx.x * 128;

    float av1[2], bv1[2], av2[2], bv2[2];
    #pragma unroll
    for (int u = 0; u < 2; ++u) {
        const int j = wn * 32 + u * 16 + l16;
        av1[u] = 0.5f * fminf(fmaxf(al1[j], 0.f), 10.f);
        bv1[u] = fminf(fmaxf(be1[j], 0.f), 10.f);
        av2[u] = 0.5f * fminf(fmaxf(al2[j], 0.f), 10.f);
        bv2[u] = fminf(fmaxf(be2[j], 0.f), 10.f);
    }

    f32x4 acc[4][4];

    // ================= stage 1: A = x (global fp32 -> bf16), B = P1, K=128 ==
    #pragma unroll
    for (int mt = 0; mt < 4; ++mt)
        #pragma unroll
        for (int nt = 0; nt < 4; ++nt) acc[mt][nt] = (f32x4){0.f, 0.f, 0.f, 0.f};

    #pragma unroll
    for (int ks = 0; ks < 4; ++ks) {
        const int k0 = ks * 32 + kg * 8;
        bf16x8 A[4];
        #pragma unroll
        for (int mt = 0; mt < 4; ++mt) {
            const float* p = x + (rowBase + mb + mt * 16 + l16) * 128 + k0;
            float4 f0 = *(const float4*)p;
            float4 f1 = *(const float4*)(p + 4);
            bf16x8 t8;
            t8[0] = (short)f2bf(f0.x); t8[1] = (short)f2bf(f0.y);
            t8[2] = (short)f2bf(f0.z); t8[3] = (short)f2bf(f0.w);
            t8[4] = (short)f2bf(f1.x); t8[5] = (short)f2bf(f1.y);
            t8[6] = (short)f2bf(f1.z); t8[7] = (short)f2bf(f1.w);
            A[mt] = t8;
        }
        #pragma unroll
        for (int nt = 0; nt < 4; ++nt) {
            bf16x8 Bf = *(const bf16x8*)&P1[(nb + nt * 16 + l16) * 128 + k0];
            #pragma unroll
            for (int mt = 0; mt < 4; ++mt)
                acc[mt][nt] = __builtin_amdgcn_mfma_f32_16x16x32_bf16(A[mt], Bf, acc[mt][nt], 0, 0, 0);
        }
    }

    // nofu1 + store to zA
    #pragma unroll
    for (int mt = 0; mt < 4; ++mt)
        #pragma unroll
        for (int u = 0; u < 2; ++u)
            #pragma unroll
            for (int r = 0; r < 4; ++r) {
                float re = acc[mt][2 * u][r], im = acc[mt][2 * u + 1][r];
                const float f = __expf(-av1[u] / (1.f + bv1[u] * (re * re + im * im + 1e-8f)));
                re *= f; im *= f;
                const int row = mb + mt * 16 + kg * 4 + r;
                const int colRe = nb + u * 32 + l16;
                const unsigned sw = (unsigned)(row & 31) << 4;
                *(u16*)(zA + (((unsigned)(row * 512 + colRe * 2)) ^ sw)) = f2bf(re);
                *(u16*)(zA + (((unsigned)(row * 512 + (colRe + 16) * 2)) ^ sw)) = f2bf(im);
            }
    __syncthreads();

    // ================= stage 2: A = zA, B = P2, K=256 =======================
    #pragma unroll
    for (int mt = 0; mt < 4; ++mt)
        #pragma unroll
        for (int nt = 0; nt < 4; ++nt) acc[mt][nt] = (f32x4){0.f, 0.f, 0.f, 0.f};

    #pragma unroll
    for (int ks = 0; ks < 8; ++ks) {
        const int k0 = ks * 32 + kg * 8;
        bf16x8 A[4];
        #pragma unroll
        for (int mt = 0; mt < 4; ++mt) {
            const int row = mb + mt * 16 + l16;
            const unsigned byte = ((unsigned)(row * 512 + k0 * 2)) ^ ((unsigned)(row & 31) << 4);
            A[mt] = *(const bf16x8*)(zA + byte);
        }
        #pragma unroll
        for (int nt = 0; nt < 4; ++nt) {
            bf16x8 Bf = *(const bf16x8*)&P2[(nb + nt * 16 + l16) * 256 + k0];
            #pragma unroll
            for (int mt = 0; mt < 4; ++mt)
                acc[mt][nt] = __builtin_amdgcn_mfma_f32_16x16x32_bf16(A[mt], Bf, acc[mt][nt], 0, 0, 0);
        }
    }
    __syncthreads();   // all zA reads done before overwrite

    // nofu2 + store to zA
    #pragma unroll
    for (int mt = 0; mt < 4; ++mt)
        #pragma unroll
        for (int u = 0; u < 2; ++u)
            #pragma unroll
            for (int r = 0; r < 4; ++r) {
                float re = acc[mt][2 * u][r], im = acc[mt][2 * u + 1][r];
                const float f = __expf(-av2[u] / (1.f + bv2[u] * (re * re + im * im + 1e-8f)));
                re *= f; im *= f;
                const int row = mb + mt * 16 + kg * 4 + r;
                const int colRe = nb + u * 32 + l16;
                const unsigned sw = (unsigned)(row & 31) << 4;
                *(u16*)(zA + (((unsigned)(row * 512 + colRe * 2)) ^ sw)) = f2bf(re);
                *(u16*)(zA + (((unsigned)(row * 512 + (colRe + 16) * 2)) ^ sw)) = f2bf(im);
            }
    __syncthreads();

    // ================= stage 3: A = zA, B = P3, K=256 (no nofu) =============
    #pragma unroll
    for (int mt = 0; mt < 4; ++mt)
        #pragma unroll
        for (int nt = 0; nt < 4; ++nt) acc[mt][nt] = (f32x4){0.f, 0.f, 0.f, 0.f};

    #pragma unroll
    for (int ks = 0; ks < 8; ++ks) {
        const int k0 = ks * 32 + kg * 8;
        bf16x8 A[4];
        #pragma unroll
        for (int mt = 0; mt < 4; ++mt) {
            const int row = mb + mt * 16 + l16;
            const unsigned byte = ((unsigned)(row * 512 + k0 * 2)) ^ ((unsigned)(row & 31) << 4);
            A[mt] = *(const bf16x8*)(zA + byte);
        }
        #pragma unroll
        for (int nt = 0; nt < 4; ++nt) {
            bf16x8 Bf = *(const bf16x8*)&P3[(nb + nt * 16 + l16) * 256 + k0];
            #pragma unroll
            for (int mt = 0; mt < 4; ++mt)
                acc[mt][nt] = __builtin_amdgcn_mfma_f32_16x16x32_bf16(A[mt], Bf, acc[mt][nt], 0, 0, 0);
        }
    }
    __syncthreads();

    // store z3 (plain) to zA
    #pragma unroll
    for (int mt = 0; mt < 4; ++mt)
        #pragma unroll
        for (int u = 0; u < 2; ++u)
            #pragma unroll
            for (int r = 0; r < 4; ++r) {
                const int row = mb + mt * 16 + kg * 4 + r;
                const int colRe = nb + u * 32 + l16;
                const unsigned sw = (unsigned)(row & 31) << 4;
                *(u16*)(zA + (((unsigned)(row * 512 + colRe * 2)) ^ sw)) = f2bf(acc[mt][2 * u][r]);
                *(u16*)(zA + (((unsigned)(row * 512 + (colRe + 16) * 2)) ^ sw)) = f2bf(acc[mt][2 * u + 1][r]);
            }
    __syncthreads();

    // ================= final: A = zA, B = P4 [128 cols][256 k], Nw=32 =======
    f32x4 facc[4][2];
    #pragma unroll
    for (int mt = 0; mt < 4; ++mt)
        #pragma unroll
        for (int nt = 0; nt < 2; ++nt) facc[mt][nt] = (f32x4){0.f, 0.f, 0.f, 0.f};

    const int nb2 = wn * 32;
    #pragma unroll
    for (int ks = 0; ks < 8; ++ks) {
        const int k0 = ks * 32 + kg * 8;
        bf16x8 A[4];
        #pragma unroll
        for (int mt = 0; mt < 4; ++mt) {
            const int row = mb + mt * 16 + l16;
            const unsigned byte = ((unsigned)(row * 512 + k0 * 2)) ^ ((unsigned)(row & 31) << 4);
            A[mt] = *(const bf16x8*)(zA + byte);
        }
        #pragma unroll
        for (int nt = 0; nt < 2; ++nt) {
            bf16x8 Bf = *(const bf16x8*)&P4[(nb2 + nt * 16 + l16) * 256 + k0];
            #pragma unroll
            for (int mt = 0; mt < 4; ++mt)
                facc[mt][nt] = __builtin_amdgcn_mfma_f32_16x16x32_bf16(A[mt], Bf, facc[mt][nt], 0, 0, 0);
        }
    }

    const float bcol0 = bias[nb2 + l16];
    const float bcol1 = bias[nb2 + 16 + l16];
    #pragma unroll
    for (int mt = 0; mt < 4; ++mt)
        #pragma unroll
        for (int r = 0; r < 4; ++r) {
            const size_t row = rowBase + mb + mt * 16 + kg * 4 + r;
            out[row * 128 + nb2 + l16]      = facc[mt][0][r] + bcol0;
            out[row * 128 + nb2 + 16 + l16] = facc[mt][1][r] + bcol1;
        }
}

extern "C" void kernel_launch(void* const* d_in, const int* in_sizes, int n_in,
                              void* d_out, int out_size, void* d_ws, size_t ws_size,
                              hipStream_t stream)
{
    const float* x      = (const float*)d_in[0];
    const float* inph   = (const float*)d_in[1];
    const float* mzi1   = (const float*)d_in[2];
    const float* outph1 = (const float*)d_in[3];
    const float* alpha1 = (const float*)d_in[4];
    const float* beta1  = (const float*)d_in[5];
    const float* mzi2   = (const float*)d_in[6];
    const float* outph2 = (const float*)d_in[7];
    const float* alpha2 = (const float*)d_in[8];
    const float* beta2  = (const float*)d_in[9];
    const float* mzi3   = (const float*)d_in[10];
    const float* outph3 = (const float*)d_in[11];
    const float* W      = (const float*)d_in[12];
    const float* bias   = (const float*)d_in[13];

    const int B = in_sizes[0] / 128;

    // ws layout
    float4* trig = (float4*)d_ws;                          // 3*128*64*16 = 393216 B
    u16* P1 = (u16*)((char*)d_ws + 393216);                // 65536 B
    u16* P2 = P1 + 32768;                                  // 131072 B
    u16* P3 = P2 + 65536;                                  // 131072 B
    u16* P4 = P3 + 65536;                                  // 65536 B

    prep_trig_kernel<<<512, 128, 0, stream>>>(mzi1, mzi2, mzi3, W, trig, P4);
    build_pack_kernel<<<384, 64, 0, stream>>>(inph, outph1, outph2, outph3, trig, P1, P2, P3);
    ficonn_mfma_kernel<<<B / 128, 512, 0, stream>>>(
        x, P1, P2, P3, P4, alpha1, beta1, alpha2, beta2, bias, (float*)d_out);
}